// Round 5
// baseline (4333.229 us; speedup 1.0000x reference)
//
#include <hip/hip_runtime.h>
#include <hip/hip_bf16.h>
#include <stdint.h>

#define B_   64
#define T_   512
#define NIN_ 256
#define N_   512

#define NGRP 4     // batch groups
#define GB   16    // batches per group
#define NSL  16    // hidden slices
#define SN   32    // neurons per slice
#define ROWU 260   // LDS th row stride in u32 (256 + 4 pad -> bank-free b128)

typedef _Float16 half8  __attribute__((ext_vector_type(8)));
typedef float    f32x4  __attribute__((ext_vector_type(4)));
typedef _Float16 half2_t __attribute__((ext_vector_type(2)));

__device__ __forceinline__ float fast_tanh(float x) {
  float e = __expf(2.0f * x);
  return 1.0f - 2.0f / (e + 1.0f);
}
__device__ __forceinline__ unsigned int packh2(float a, float b) {
  half2_t h; h[0] = (_Float16)a; h[1] = (_Float16)b;
  return __builtin_bit_cast(unsigned int, h);
}

// ---------------- Phase 1: xp[b,t,n] = sum_c x[b,t,c] * Wih[n,c] -> out ----
__global__ __launch_bounds__(256) void xproj(const float* __restrict__ x,
                                             const float* __restrict__ Wih,
                                             float* __restrict__ out) {
  const int tid = threadIdx.x;
  const int bm = blockIdx.x;
  const int bn = blockIdx.y;
  const int tm = tid & 15;
  const int tn = tid >> 4;
  const int m0 = bm << 7;
  const int n0 = bn << 7;

  __shared__ float xt[32][132];
  __shared__ float wt[32][132];

  float acc[8][8];
#pragma unroll
  for (int i = 0; i < 8; ++i)
#pragma unroll
    for (int j = 0; j < 8; ++j) acc[i][j] = 0.f;

  for (int ko = 0; ko < NIN_; ko += 32) {
#pragma unroll
    for (int it = 0; it < 4; ++it) {
      const int fidx = it * 256 + tid;
      const int mm = fidx >> 3;
      const int k4 = (fidx & 7) << 2;
      const float4 vx = *(const float4*)(x + (size_t)(m0 + mm) * NIN_ + ko + k4);
      xt[k4 + 0][mm] = vx.x; xt[k4 + 1][mm] = vx.y;
      xt[k4 + 2][mm] = vx.z; xt[k4 + 3][mm] = vx.w;
      const float4 vw = *(const float4*)(Wih + (size_t)(n0 + mm) * NIN_ + ko + k4);
      wt[k4 + 0][mm] = vw.x; wt[k4 + 1][mm] = vw.y;
      wt[k4 + 2][mm] = vw.z; wt[k4 + 3][mm] = vw.w;
    }
    __syncthreads();
#pragma unroll 4
    for (int kk = 0; kk < 32; ++kk) {
      float a[8], b[8];
      *(float4*)&a[0] = *(const float4*)&xt[kk][8 * tm];
      *(float4*)&a[4] = *(const float4*)&xt[kk][8 * tm + 4];
      *(float4*)&b[0] = *(const float4*)&wt[kk][8 * tn];
      *(float4*)&b[4] = *(const float4*)&wt[kk][8 * tn + 4];
#pragma unroll
      for (int i = 0; i < 8; ++i)
#pragma unroll
        for (int j = 0; j < 8; ++j) acc[i][j] = fmaf(a[i], b[j], acc[i][j]);
    }
    __syncthreads();
  }

#pragma unroll
  for (int i = 0; i < 8; ++i) {
    float4 v0 = make_float4(acc[i][0], acc[i][1], acc[i][2], acc[i][3]);
    float4 v1 = make_float4(acc[i][4], acc[i][5], acc[i][6], acc[i][7]);
    float* p = out + (size_t)(m0 + 8 * tm + i) * N_ + n0 + 8 * tn;
    *(float4*)p = v0;
    *((float4*)p + 1) = v1;
  }
}

// ---------------- Phase 2: MFMA recurrent scan ----------------------------
// 64 blocks x 256 thr. block: group g=blk&3 (16 batches), slice s=blk>>2
// (32 neurons). Waves 0-1: one 16x16x32 f16 MFMA tile each (16n x 16b),
// weights = 16 A-fragments in VGPR (64 u32, proven-safe). Waves 2-3: stagers
// polling tagged u64 packets {t, 2xf16 tanh} from the exchange buffer into
// double-buffered LDS th. A and B use the SAME lane->k mapping, so the
// contraction is invariant to the exact k permutation; C/D layout is the
// m89-verified (col=lane&15, row=(lane>>4)*4+reg).
__global__ __launch_bounds__(256, 1) void rnn_scan(const float* __restrict__ Whh,
                                                   float* __restrict__ out,
                                                   unsigned long long* __restrict__ ex) {
  const int blk = blockIdx.x;
  const int g = blk & (NGRP - 1);
  const int s = blk >> 2;
  const int tid = threadIdx.x;
  const int wv = tid >> 6;
  const int l  = tid & 63;

  __shared__ __align__(16) unsigned int th[2][GB][ROWU];

  // ---- t=0 staging: th[0] = tanh(out[g*16+b][0][:]) for the group's 16 b --
  {
    const int b = tid >> 4;
    const int c = tid & 15;
    const float* src = out + (size_t)(g * GB + b) * T_ * N_ + c * 32;
    unsigned int vals[16];
#pragma unroll
    for (int i = 0; i < 16; ++i) {
      float2 v = *(const float2*)(src + 2 * i);
      vals[i] = packh2(fast_tanh(v.x), fast_tanh(v.y));
    }
#pragma unroll
    for (int j = 0; j < 4; ++j)
      *(uint4*)&th[0][b][c * 16 + 4 * j] =
          make_uint4(vals[4 * j], vals[4 * j + 1], vals[4 * j + 2], vals[4 * j + 3]);
  }

  if (wv < 2) {
    // ------------------- MFMA role (waves 0,1) ---------------------------
    const int w  = wv;
    const int bc = l & 15;                 // A-row idx == D-col (batch)
    const int ko = l >> 4;                 // k-octet selector
    const int gn = s * SN + w * 16 + bc;   // neuron of my A-row
    const int gb = g * GB + bc;            // my D-column's global batch
    const int n0 = s * SN + w * 16 + ko * 4;  // first of my 4 D-row neurons
    const int kp0 = w * 8 + ko * 2;        // within-slice k-pair of my D rows

    half8 wf[16];
#pragma unroll
    for (int ks = 0; ks < 16; ++ks) {
      const float* wr = Whh + (size_t)gn * N_ + ks * 32 + ko * 8;
      float4 w0 = *(const float4*)wr;
      float4 w1 = *(const float4*)(wr + 4);
      half8 h;
      h[0] = (_Float16)w0.x; h[1] = (_Float16)w0.y;
      h[2] = (_Float16)w0.z; h[3] = (_Float16)w0.w;
      h[4] = (_Float16)w1.x; h[5] = (_Float16)w1.y;
      h[6] = (_Float16)w1.z; h[7] = (_Float16)w1.w;
      wf[ks] = h;
    }
    __syncthreads();   // th[0] staged; matches stager pre-loop barrier

    for (int t = 1; t < T_; ++t) {
      float4 xp = *(const float4*)(out + ((size_t)gb * T_ + t) * N_ + n0);
      f32x4 acc = {0.f, 0.f, 0.f, 0.f};
      const unsigned int* tb = &th[(t - 1) & 1][bc][0];
#pragma unroll
      for (int ks = 0; ks < 16; ++ks) {
        uint4 bv = *(const uint4*)(tb + ks * 16 + ko * 4);
        acc = __builtin_amdgcn_mfma_f32_16x16x32_f16(
            wf[ks], __builtin_bit_cast(half8, bv), acc, 0, 0, 0);
      }
      const float y0 = acc[0] + xp.x;
      const float y1 = acc[1] + xp.y;
      const float y2 = acc[2] + xp.z;
      const float y3 = acc[3] + xp.w;
      *(float4*)(out + ((size_t)gb * T_ + t) * N_ + n0) = make_float4(y0, y1, y2, y3);
      const unsigned int p0 = packh2(fast_tanh(y0), fast_tanh(y1));
      const unsigned int p1 = packh2(fast_tanh(y2), fast_tanh(y3));
      const size_t base =
          ((((size_t)g * 2 + (t & 1)) * NSL + s) * GB + bc) * 16 + kp0;
      const unsigned long long tg = (unsigned long long)(unsigned int)t << 32;
      __hip_atomic_store(&ex[base],     tg | p0, __ATOMIC_RELAXED,
                         __HIP_MEMORY_SCOPE_AGENT);
      __hip_atomic_store(&ex[base + 1], tg | p1, __ATOMIC_RELAXED,
                         __HIP_MEMORY_SCOPE_AGENT);
      __syncthreads();
    }
  } else {
    // ------------------- stager role (waves 2,3) -------------------------
    const int tau = tid - 128;   // 0..127
    __syncthreads();             // matches MFMA pre-loop barrier
    for (int t = 1; t < T_; ++t) {
      if (t < T_ - 1) {
#pragma unroll 1
        for (int pp = 0; pp < 2; ++pp) {
          const int p  = tau + pp * 128;   // 0..255 = (slice, batch)
          const int sp = p >> 4;
          const int b  = p & 15;
          const size_t base =
              ((((size_t)g * 2 + (t & 1)) * NSL + sp) * GB + b) * 16;
          unsigned long long v[16];
          bool ok;
          do {
            ok = true;
#pragma unroll
            for (int i = 0; i < 16; ++i) {
              v[i] = __hip_atomic_load(&ex[base + i], __ATOMIC_RELAXED,
                                       __HIP_MEMORY_SCOPE_AGENT);
              ok = ok && ((unsigned int)(v[i] >> 32) == (unsigned int)t);
            }
          } while (!ok);
#pragma unroll
          for (int j = 0; j < 4; ++j)
            *(uint4*)&th[t & 1][b][sp * 16 + 4 * j] =
                make_uint4((unsigned int)v[4 * j],     (unsigned int)v[4 * j + 1],
                           (unsigned int)v[4 * j + 2], (unsigned int)v[4 * j + 3]);
        }
      }
      __syncthreads();
    }
  }
}

extern "C" void kernel_launch(void* const* d_in, const int* in_sizes, int n_in,
                              void* d_out, int out_size, void* d_ws, size_t ws_size,
                              hipStream_t stream) {
  const float* x   = (const float*)d_in[0];
  const float* Wih = (const float*)d_in[1];
  const float* Whh = (const float*)d_in[2];
  float* out = (float*)d_out;
  unsigned long long* ex = (unsigned long long*)d_ws;

  // exchange: 4 groups x 2 slots x 16 slices x 16 b x 16 kp x 8B = 256 KiB
  hipMemsetAsync(d_ws, 0, (size_t)NGRP * 2 * NSL * GB * 16 * 8, stream);

  dim3 g1(256, 4);
  xproj<<<g1, 256, 0, stream>>>(x, Wih, out);
  rnn_scan<<<NGRP * NSL, 256, 0, stream>>>(Whh, out, ex);
}

// Round 6
// 1721.505 us; speedup vs baseline: 2.5171x; 2.5171x over previous
//
#include <hip/hip_runtime.h>
#include <stdint.h>

#define B_   64
#define T_   512
#define NIN_ 256
#define N_   512
#define ROWU 260   // th row stride in u32

typedef _Float16 half8   __attribute__((ext_vector_type(8)));
typedef float    f32x4   __attribute__((ext_vector_type(4)));
typedef _Float16 half2_t __attribute__((ext_vector_type(2)));

__device__ __forceinline__ float fast_tanh(float x) {
  float e = __expf(2.0f * x);
  return 1.0f - 2.0f / (e + 1.0f);
}
__device__ __forceinline__ unsigned int packh2(float a, float b) {
  half2_t h; h[0] = (_Float16)a; h[1] = (_Float16)b;
  return __builtin_bit_cast(unsigned int, h);
}

// Fused kernel: blocks 0..63 = recurrent scan (8 groups x 8 slices),
// blocks 64..255 = xproj GEMM (xp[b,t,n] -> out), t-chunk-major order with
// release-fenced completion counters; scan gates on them at chunk starts.
__global__ __launch_bounds__(512, 1) void rnn_fused(
    const float* __restrict__ x, const float* __restrict__ Wih,
    const float* __restrict__ Whh, float* __restrict__ out,
    unsigned long long* __restrict__ ex, int* __restrict__ flags) {
  const int blk = blockIdx.x;
  const int tid = threadIdx.x;

  __shared__ __align__(16) unsigned int th[2][16][ROWU];  // scan role
  __shared__ float xt[32][132];                           // xproj role
  __shared__ float wt[32][132];

  if (blk >= 64) {
    // ================= xproj role =================
    const int tm2 = tid >> 5;   // 0..15 -> 8 m-rows each
    const int tn2 = tid & 31;   // 0..31 -> 4 n-cols each
    for (int tau = blk - 64; tau < 1024; tau += 192) {
      // chunk-major: tc = tau>>8 so chunk 0 tiles finish first
      const int tc = tau >> 8;
      const int j  = tau & 255;
      const int b  = j >> 2;
      const int bn = j & 3;
      const int bm = b * 4 + tc;
      const int m0 = bm << 7;
      const int nn0 = bn << 7;

      float acc[8][4];
#pragma unroll
      for (int i = 0; i < 8; ++i)
#pragma unroll
        for (int jj = 0; jj < 4; ++jj) acc[i][jj] = 0.f;

      for (int ko2 = 0; ko2 < NIN_; ko2 += 32) {
#pragma unroll
        for (int it = 0; it < 2; ++it) {
          const int fidx = it * 512 + tid;      // 0..1023
          const int mm = fidx >> 3;
          const int k4 = (fidx & 7) << 2;
          const float4 vx = *(const float4*)(x + (size_t)(m0 + mm) * NIN_ + ko2 + k4);
          xt[k4 + 0][mm] = vx.x; xt[k4 + 1][mm] = vx.y;
          xt[k4 + 2][mm] = vx.z; xt[k4 + 3][mm] = vx.w;
          const float4 vw = *(const float4*)(Wih + (size_t)(nn0 + mm) * NIN_ + ko2 + k4);
          wt[k4 + 0][mm] = vw.x; wt[k4 + 1][mm] = vw.y;
          wt[k4 + 2][mm] = vw.z; wt[k4 + 3][mm] = vw.w;
        }
        __syncthreads();
#pragma unroll 4
        for (int kk = 0; kk < 32; ++kk) {
          float a[8], bb[4];
          *(float4*)&a[0] = *(const float4*)&xt[kk][8 * tm2];
          *(float4*)&a[4] = *(const float4*)&xt[kk][8 * tm2 + 4];
          *(float4*)&bb[0] = *(const float4*)&wt[kk][4 * tn2];
#pragma unroll
          for (int i = 0; i < 8; ++i)
#pragma unroll
            for (int jj = 0; jj < 4; ++jj)
              acc[i][jj] = fmaf(a[i], bb[jj], acc[i][jj]);
        }
        __syncthreads();
      }
#pragma unroll
      for (int i = 0; i < 8; ++i) {
        *(float4*)(out + (size_t)(m0 + 8 * tm2 + i) * N_ + nn0 + 4 * tn2) =
            make_float4(acc[i][0], acc[i][1], acc[i][2], acc[i][3]);
      }
      __threadfence();       // make this tile's stores agent-visible
      __syncthreads();       // all threads' fences done
      if (tid == 0)
        __hip_atomic_fetch_add(&flags[tc], 1, __ATOMIC_RELEASE,
                               __HIP_MEMORY_SCOPE_AGENT);
    }
    return;
  }

  // ================= scan role =================
  const int g = blk & 7;    // group: batches g*8 .. g*8+7
  const int m = blk >> 3;   // slice: neurons m*64 .. m*64+63
  const int wv = tid >> 6;
  const int l  = tid & 63;

  // ---- compute-wave constants & weight A-fragments (R5-verified layout) ----
  const int w  = wv;        // tile within slice (wv<4)
  const int bc = l & 15;    // A-row / D-col
  const int ko = l >> 4;    // k-octet
  half8 wf[16];
  if (wv < 4) {
    const int arow = m * 64 + w * 16 + bc;
#pragma unroll
    for (int ks = 0; ks < 16; ++ks) {
      const float* wr = Whh + (size_t)arow * N_ + ks * 32 + ko * 8;
      const float4 w0 = *(const float4*)wr;
      const float4 w1 = *(const float4*)(wr + 4);
      half8 h;
      h[0] = (_Float16)w0.x; h[1] = (_Float16)w0.y;
      h[2] = (_Float16)w0.z; h[3] = (_Float16)w0.w;
      h[4] = (_Float16)w1.x; h[5] = (_Float16)w1.y;
      h[6] = (_Float16)w1.z; h[7] = (_Float16)w1.w;
      wf[ks] = h;
    }
  }

  // ---- gate on xp chunk 0 (also covers the t=0 row init below) ----
  if (tid == 0) {
    while (__hip_atomic_load(&flags[0], __ATOMIC_ACQUIRE,
                             __HIP_MEMORY_SCOPE_AGENT) < 256) {}
  }
  __syncthreads();

  // ---- init LDS: zero rows 8..15 (both slots), stage tanh(h_1) rows 0..7 --
  for (int i = tid; i < 2 * 8 * ROWU; i += 512) {
    const int slot = i / (8 * ROWU);
    const int r = (i / ROWU) & 7;
    const int c = i % ROWU;
    th[slot][8 + r][c] = 0u;
  }
  for (int i = tid; i < 2048; i += 512) {
    const int b = i >> 8;
    const int c = i & 255;
    const float2 h0 = *(const float2*)(out + (size_t)(g * 8 + b) * T_ * N_ + 2 * c);
    th[0][b][c] = packh2(fast_tanh(h0.x), fast_tanh(h0.y));
  }
  __syncthreads();

  // ---- per-role constants ----
  const int gb = g * 8 + bc;                       // global batch (valid bc<8)
  const int n0 = m * 64 + w * 16 + ko * 4;         // first D-row neuron
  const int np0 = w * 8 + ko * 2;                  // pair index within slice
  const size_t outrow = (size_t)gb * T_ * N_;

  const int lam = tid - 256;                       // stager lane 0..255
  const int sb  = lam >> 5;                        // batch row 0..7
  const int snp = lam & 31;                        // pair col 0..31
  int mrs[7];
#pragma unroll
  for (int i = 0; i < 7; ++i) mrs[i] = i + (i >= m ? 1 : 0);

  for (int t = 1; t < T_; ++t) {
    if ((t & 127) == 0) {                          // xp chunk gate (t=128,256,384)
      if (tid == 0) {
        while (__hip_atomic_load(&flags[t >> 7], __ATOMIC_ACQUIRE,
                                 __HIP_MEMORY_SCOPE_AGENT) < 256) {}
      }
      __syncthreads();
    }

    if (wv < 4) {
      // ---- compute: one 16x16x32 f16 MFMA tile, two half-K chains ----
      float4 xp = make_float4(0.f, 0.f, 0.f, 0.f);
      if (bc < 8) xp = *(const float4*)(out + outrow + (size_t)t * N_ + n0);

      const unsigned int* tb = &th[(t - 1) & 1][bc][0];
      f32x4 a0 = {0.f, 0.f, 0.f, 0.f};
      f32x4 a1 = {0.f, 0.f, 0.f, 0.f};
#pragma unroll
      for (int ks = 0; ks < 8; ++ks) {
        const uint4 b0 = *(const uint4*)(tb + ks * 16 + ko * 4);
        const uint4 b1 = *(const uint4*)(tb + (ks + 8) * 16 + ko * 4);
        a0 = __builtin_amdgcn_mfma_f32_16x16x32_f16(
            wf[ks], __builtin_bit_cast(half8, b0), a0, 0, 0, 0);
        a1 = __builtin_amdgcn_mfma_f32_16x16x32_f16(
            wf[ks + 8], __builtin_bit_cast(half8, b1), a1, 0, 0, 0);
      }
      const f32x4 acc = a0 + a1;

      if (bc < 8) {
        const float y0 = acc[0] + xp.x;
        const float y1 = acc[1] + xp.y;
        const float y2 = acc[2] + xp.z;
        const float y3 = acc[3] + xp.w;
        *(float4*)(out + outrow + (size_t)t * N_ + n0) = make_float4(y0, y1, y2, y3);
        const unsigned int p0 = packh2(fast_tanh(y0), fast_tanh(y1));
        const unsigned int p1 = packh2(fast_tanh(y2), fast_tanh(y3));
        th[t & 1][bc][m * 32 + np0]     = p0;
        th[t & 1][bc][m * 32 + np0 + 1] = p1;
        const size_t eb =
            ((((size_t)g * 2 + (t & 1)) * 8 + m) * 8 + bc) * 32 + np0;
        const unsigned long long tg = (unsigned long long)(unsigned int)t << 32;
        __hip_atomic_store(&ex[eb], tg | p0, __ATOMIC_RELAXED,
                           __HIP_MEMORY_SCOPE_AGENT);
        __hip_atomic_store(&ex[eb + 1], tg | p1, __ATOMIC_RELAXED,
                           __HIP_MEMORY_SCOPE_AGENT);
      }
    } else if (t < T_ - 1) {
      // ---- stagers: 7 remote packets, parallel loads, batched retry ----
      const unsigned long long* ap[7];
#pragma unroll
      for (int i = 0; i < 7; ++i)
        ap[i] = &ex[((((size_t)g * 2 + (t & 1)) * 8 + mrs[i]) * 8 + sb) * 32 + snp];
      unsigned long long v[7];
      bool all;
      do {
#pragma unroll
        for (int i = 0; i < 7; ++i)
          v[i] = __hip_atomic_load(ap[i], __ATOMIC_RELAXED,
                                   __HIP_MEMORY_SCOPE_AGENT);
        all = true;
#pragma unroll
        for (int i = 0; i < 7; ++i)
          all = all && ((unsigned int)(v[i] >> 32) == (unsigned int)t);
      } while (!all);
#pragma unroll
      for (int i = 0; i < 7; ++i)
        th[t & 1][sb][mrs[i] * 32 + snp] = (unsigned int)v[i];
    }
    __syncthreads();   // publishes th[t&1] (own + staged remote) for t+1
  }
}

extern "C" void kernel_launch(void* const* d_in, const int* in_sizes, int n_in,
                              void* d_out, int out_size, void* d_ws, size_t ws_size,
                              hipStream_t stream) {
  const float* x   = (const float*)d_in[0];
  const float* Wih = (const float*)d_in[1];
  const float* Whh = (const float*)d_in[2];
  float* out = (float*)d_out;
  unsigned long long* ex = (unsigned long long*)d_ws;          // 256 KiB
  int* flags = (int*)((char*)d_ws + 262144);                   // 4 ints

  hipMemsetAsync(d_ws, 0, 262144 + 64, stream);
  rnn_fused<<<256, 512, 0, stream>>>(x, Wih, Whh, out, ex, flags);
}

// Round 7
// 1692.221 us; speedup vs baseline: 2.5607x; 1.0173x over previous
//
#include <hip/hip_runtime.h>
#include <stdint.h>

#define B_   64
#define T_   512
#define NIN_ 256
#define N_   512
#define ROWU 260   // th row stride in u32

typedef _Float16 half8   __attribute__((ext_vector_type(8)));
typedef float    f32x4   __attribute__((ext_vector_type(4)));
typedef _Float16 half2_t __attribute__((ext_vector_type(2)));

__device__ __forceinline__ float fast_tanh(float x) {
  float e = __expf(2.0f * x);
  return 1.0f - 2.0f / (e + 1.0f);
}
__device__ __forceinline__ unsigned int packh2(float a, float b) {
  half2_t h; h[0] = (_Float16)a; h[1] = (_Float16)b;
  return __builtin_bit_cast(unsigned int, h);
}

// ---------------- Phase 1: xp[b,t,n] = sum_c x[b,t,c] * Wih[n,c] -> out ----
__global__ __launch_bounds__(256) void xproj(const float* __restrict__ x,
                                             const float* __restrict__ Wih,
                                             float* __restrict__ out) {
  const int tid = threadIdx.x;
  const int bm = blockIdx.x;
  const int bn = blockIdx.y;
  const int tm = tid & 15;
  const int tn = tid >> 4;
  const int m0 = bm << 7;
  const int n0 = bn << 7;

  __shared__ float xt[32][132];
  __shared__ float wt[32][132];

  float acc[8][8];
#pragma unroll
  for (int i = 0; i < 8; ++i)
#pragma unroll
    for (int j = 0; j < 8; ++j) acc[i][j] = 0.f;

  for (int ko = 0; ko < NIN_; ko += 32) {
#pragma unroll
    for (int it = 0; it < 4; ++it) {
      const int fidx = it * 256 + tid;
      const int mm = fidx >> 3;
      const int k4 = (fidx & 7) << 2;
      const float4 vx = *(const float4*)(x + (size_t)(m0 + mm) * NIN_ + ko + k4);
      xt[k4 + 0][mm] = vx.x; xt[k4 + 1][mm] = vx.y;
      xt[k4 + 2][mm] = vx.z; xt[k4 + 3][mm] = vx.w;
      const float4 vw = *(const float4*)(Wih + (size_t)(n0 + mm) * NIN_ + ko + k4);
      wt[k4 + 0][mm] = vw.x; wt[k4 + 1][mm] = vw.y;
      wt[k4 + 2][mm] = vw.z; wt[k4 + 3][mm] = vw.w;
    }
    __syncthreads();
#pragma unroll 4
    for (int kk = 0; kk < 32; ++kk) {
      float a[8], b[8];
      *(float4*)&a[0] = *(const float4*)&xt[kk][8 * tm];
      *(float4*)&a[4] = *(const float4*)&xt[kk][8 * tm + 4];
      *(float4*)&b[0] = *(const float4*)&wt[kk][8 * tn];
      *(float4*)&b[4] = *(const float4*)&wt[kk][8 * tn + 4];
#pragma unroll
      for (int i = 0; i < 8; ++i)
#pragma unroll
        for (int j = 0; j < 8; ++j) acc[i][j] = fmaf(a[i], b[j], acc[i][j]);
    }
    __syncthreads();
  }

#pragma unroll
  for (int i = 0; i < 8; ++i) {
    float4 v0 = make_float4(acc[i][0], acc[i][1], acc[i][2], acc[i][3]);
    float4 v1 = make_float4(acc[i][4], acc[i][5], acc[i][6], acc[i][7]);
    float* p = out + (size_t)(m0 + 8 * tm + i) * N_ + n0 + 8 * tn;
    *(float4*)p = v0;
    *((float4*)p + 1) = v1;
  }
}

// ---------------- Phase 2: MFMA recurrent scan, runtime XCD grouping ------
// Launch 256 blocks x 512 thr. Each block reads its physical XCC_ID and
// registers; the first 8 registrants on XCD x become group x's 8 slices
// (batches x*8..x*8+7, slice = 64 neurons). Surplus blocks adopt leftover
// slices (cross-XCD fallback -> placement-independent correctness) or exit.
// Waves 0-3: one 16x16x32 f16 MFMA tile each; 16 A-fragments in NAMED half8
// registers (no array -> no scratch demotion), loaded by ALL waves (R4's
// proven-resident pattern). Waves 4-7: stagers polling 7 remote slices'
// tagged u64 packets {t, 2xf16 tanh} into double-buffered LDS.
__global__ __launch_bounds__(512, 1) void rnn_scan(
    const float* __restrict__ Whh, float* __restrict__ out,
    unsigned long long* __restrict__ ex, int* __restrict__ ctrl) {
  const int tid = threadIdx.x;
  const int wv = tid >> 6;
  const int l  = tid & 63;

  __shared__ __align__(16) unsigned int th[2][16][ROWU];
  __shared__ int bcastg, bcasts;

  // ---- registration: discover physical XCD, claim (group, slice) ----
  if (tid == 0) {
    const int xcd = __builtin_amdgcn_s_getreg((31 << 11) | 20) & 7;  // HW_REG_XCC_ID
    const int slot = __hip_atomic_fetch_add(&ctrl[xcd], 1, __ATOMIC_RELAXED,
                                            __HIP_MEMORY_SCOPE_AGENT);
    int srank = -1;
    if (slot >= 8)
      srank = __hip_atomic_fetch_add(&ctrl[8], 1, __ATOMIC_RELAXED,
                                     __HIP_MEMORY_SCOPE_AGENT);
    __hip_atomic_fetch_add(&ctrl[9], 1, __ATOMIC_RELEASE,
                           __HIP_MEMORY_SCOPE_AGENT);
    while (__hip_atomic_load(&ctrl[9], __ATOMIC_ACQUIRE,
                             __HIP_MEMORY_SCOPE_AGENT) != (int)gridDim.x)
      __builtin_amdgcn_s_sleep(1);
    int g = -1, s = -1;
    if (slot < 8) {
      g = xcd; s = slot;
    } else {
      int r = srank;
#pragma unroll
      for (int xx = 0; xx < 8; ++xx) {
        const int c = __hip_atomic_load(&ctrl[xx], __ATOMIC_RELAXED,
                                        __HIP_MEMORY_SCOPE_AGENT);
        const int filled = c < 8 ? c : 8;
        const int d = 8 - filled;
        if (g < 0 && r < d) { g = xx; s = filled + r; }
        if (g < 0) r -= d;
      }
    }
    bcastg = g; bcasts = s;
  }
  __syncthreads();
  const int g = bcastg;
  const int m = bcasts;
  if (g < 0) return;   // surplus block, no leftover work

  // ---- weight A-fragments: 16 NAMED half8 regs, loaded by ALL waves ----
  const int bc = l & 15;    // A-row / D-col
  const int ko = l >> 4;    // k-octet
  const int arow = m * 64 + (wv & 3) * 16 + bc;
  const float* wbase = Whh + (size_t)arow * N_ + ko * 8;
#define LDW(KS)                                                        \
  half8 wf##KS;                                                        \
  {                                                                    \
    const float* wr = wbase + (KS) * 32;                               \
    const float4 w0 = *(const float4*)wr;                              \
    const float4 w1 = *(const float4*)(wr + 4);                        \
    wf##KS[0] = (_Float16)w0.x; wf##KS[1] = (_Float16)w0.y;            \
    wf##KS[2] = (_Float16)w0.z; wf##KS[3] = (_Float16)w0.w;            \
    wf##KS[4] = (_Float16)w1.x; wf##KS[5] = (_Float16)w1.y;            \
    wf##KS[6] = (_Float16)w1.z; wf##KS[7] = (_Float16)w1.w;            \
  }
  LDW(0) LDW(1) LDW(2) LDW(3) LDW(4) LDW(5) LDW(6) LDW(7)
  LDW(8) LDW(9) LDW(10) LDW(11) LDW(12) LDW(13) LDW(14) LDW(15)
#undef LDW

  // ---- init LDS: zero rows 8..15 (both slots), stage tanh(h_1) rows 0..7 --
  for (int i = tid; i < 2 * 8 * ROWU; i += 512) {
    const int slot = i / (8 * ROWU);
    const int r = (i / ROWU) & 7;
    const int c = i % ROWU;
    th[slot][8 + r][c] = 0u;
  }
  for (int i = tid; i < 2048; i += 512) {
    const int b = i >> 8;
    const int c = i & 255;
    const float2 h0 = *(const float2*)(out + (size_t)(g * 8 + b) * T_ * N_ + 2 * c);
    th[0][b][c] = packh2(fast_tanh(h0.x), fast_tanh(h0.y));
  }
  __syncthreads();

  // ---- per-role constants ----
  const int gb = g * 8 + bc;                       // global batch (valid bc<8)
  const int n0 = m * 64 + (wv & 3) * 16 + ko * 4;  // first D-row neuron
  const int np0 = (wv & 3) * 8 + ko * 2;           // pair idx within slice
  const size_t outrow = (size_t)gb * T_ * N_;

  const int lam = tid - 256;                       // stager lane 0..255
  const int sb  = lam >> 5;                        // batch row 0..7
  const int snp = lam & 31;                        // pair col 0..31
  int mrs[7];
#pragma unroll
  for (int i = 0; i < 7; ++i) mrs[i] = i + (i >= m ? 1 : 0);

  for (int t = 1; t < T_; ++t) {
    if (wv < 4) {
      // ---- compute: one 16x16x32 f16 MFMA tile (two half-K chains) ----
      float4 xp = make_float4(0.f, 0.f, 0.f, 0.f);
      if (bc < 8) xp = *(const float4*)(out + outrow + (size_t)t * N_ + n0);

      const unsigned int* tb = &th[(t - 1) & 1][bc][0];
      f32x4 a0 = {0.f, 0.f, 0.f, 0.f};
      f32x4 a1 = {0.f, 0.f, 0.f, 0.f};
#define MM(KS, KS2)                                                        \
  {                                                                        \
    const uint4 b0 = *(const uint4*)(tb + (KS) * 16 + ko * 4);             \
    const uint4 b1 = *(const uint4*)(tb + (KS2) * 16 + ko * 4);            \
    a0 = __builtin_amdgcn_mfma_f32_16x16x32_f16(                           \
        wf##KS, __builtin_bit_cast(half8, b0), a0, 0, 0, 0);               \
    a1 = __builtin_amdgcn_mfma_f32_16x16x32_f16(                           \
        wf##KS2, __builtin_bit_cast(half8, b1), a1, 0, 0, 0);              \
  }
      MM(0, 8) MM(1, 9) MM(2, 10) MM(3, 11)
      MM(4, 12) MM(5, 13) MM(6, 14) MM(7, 15)
#undef MM
      const f32x4 acc = a0 + a1;

      if (bc < 8) {
        const float y0 = acc[0] + xp.x;
        const float y1 = acc[1] + xp.y;
        const float y2 = acc[2] + xp.z;
        const float y3 = acc[3] + xp.w;
        const unsigned int p0 = packh2(fast_tanh(y0), fast_tanh(y1));
        const unsigned int p1 = packh2(fast_tanh(y2), fast_tanh(y3));
        // publish FIRST: cross-CU critical path
        const size_t eb =
            ((((size_t)g * 2 + (t & 1)) * 8 + m) * 8 + bc) * 32 + np0;
        const unsigned long long tg = (unsigned long long)(unsigned int)t << 32;
        __hip_atomic_store(&ex[eb], tg | p0, __ATOMIC_RELAXED,
                           __HIP_MEMORY_SCOPE_AGENT);
        __hip_atomic_store(&ex[eb + 1], tg | p1, __ATOMIC_RELAXED,
                           __HIP_MEMORY_SCOPE_AGENT);
        th[t & 1][bc][m * 32 + np0]     = p0;
        th[t & 1][bc][m * 32 + np0 + 1] = p1;
        *(float4*)(out + outrow + (size_t)t * N_ + n0) =
            make_float4(y0, y1, y2, y3);
      }
    } else if (t < T_ - 1) {
      // ---- stagers: 7 remote packets, parallel loads, batched retry ----
      const unsigned long long* ap[7];
#pragma unroll
      for (int i = 0; i < 7; ++i)
        ap[i] = &ex[((((size_t)g * 2 + (t & 1)) * 8 + mrs[i]) * 8 + sb) * 32 + snp];
      unsigned long long v[7];
      bool all;
      do {
#pragma unroll
        for (int i = 0; i < 7; ++i)
          v[i] = __hip_atomic_load(ap[i], __ATOMIC_RELAXED,
                                   __HIP_MEMORY_SCOPE_AGENT);
        all = true;
#pragma unroll
        for (int i = 0; i < 7; ++i)
          all = all && ((unsigned int)(v[i] >> 32) == (unsigned int)t);
      } while (!all);
#pragma unroll
      for (int i = 0; i < 7; ++i)
        th[t & 1][sb][mrs[i] * 32 + snp] = (unsigned int)v[i];
    }
    __syncthreads();   // publishes th[t&1] (own + staged remote) for t+1
  }
}

extern "C" void kernel_launch(void* const* d_in, const int* in_sizes, int n_in,
                              void* d_out, int out_size, void* d_ws, size_t ws_size,
                              hipStream_t stream) {
  const float* x   = (const float*)d_in[0];
  const float* Wih = (const float*)d_in[1];
  const float* Whh = (const float*)d_in[2];
  float* out = (float*)d_out;
  unsigned long long* ex = (unsigned long long*)d_ws;   // 256 KiB exchange
  int* ctrl = (int*)((char*)d_ws + 262144);             // cnt[8], surplus, done

  hipMemsetAsync(d_ws, 0, 262144 + 64, stream);
  dim3 g1(256, 4);
  xproj<<<g1, 256, 0, stream>>>(x, Wih, out);
  rnn_scan<<<256, 512, 0, stream>>>(Whh, out, ex, ctrl);
}